// Round 18
// baseline (237.145 us; speedup 1.0000x reference)
//
#include <hip/hip_runtime.h>

#define DIM 128
#define SLOTS 64

typedef __attribute__((ext_vector_type(8))) short bf16x8;
typedef __attribute__((ext_vector_type(4))) float f32x4;
typedef __attribute__((ext_vector_type(2))) float f32x2;
typedef unsigned short u16;
typedef unsigned int u32;
typedef unsigned long long u64;

__device__ __forceinline__ float bf2f(u32 u) {
    return __builtin_bit_cast(float, u << 16);
}
__device__ __forceinline__ u16 f2bf(float f) {
    u32 u = __builtin_bit_cast(u32, f);
    u = (u + 0x7FFFu + ((u >> 16) & 1u)) >> 16;   // RNE
    return (u16)u;
}
__device__ __forceinline__ u32 pack2bf(float a, float b) {
    return (u32)f2bf(a) | ((u32)f2bf(b) << 16);
}

// ---------------- k_hist: atomic-free in-degree via LDS-privatized histograms ----------------

__global__ __launch_bounds__(1024) void k_hist(const int* __restrict__ col, int E,
                                               int* __restrict__ part, int N) {
    __shared__ int hist[12544];
    int b = blockIdx.x;            // 0..31
    int range = b >> 3;            // 0..3
    int chunk = b & 7;             // 0..7
    int quarter = (N + 3) >> 2;
    int base = range * quarter;
    int hn = N - base; if (hn > quarter) hn = quarter;
    for (int i = threadIdx.x; i < hn; i += 1024) hist[i] = 0;
    __syncthreads();
    int e0 = (int)((long long)chunk * E / 8);
    int e1 = (int)((long long)(chunk + 1) * E / 8);
    for (int e = e0 + threadIdx.x; e < e1; e += 1024) {
        int c = col[e] - base;
        if ((u32)c < (u32)hn) atomicAdd(&hist[c], 1);   // LDS atomic
    }
    __syncthreads();
    int* dst = part + (size_t)b * quarter;
    for (int i = threadIdx.x; i < hn; i += 1024) dst[i] = hist[i];
}

__global__ void k_dis2(const int* __restrict__ part, float* __restrict__ dis, int N) {
    int i = blockIdx.x * 256 + threadIdx.x;
    if (i >= N) return;
    int quarter = (N + 3) >> 2;
    int range = i / quarter;
    int il = i - range * quarter;
    const int* p = part + ((size_t)range * 8) * quarter + il;
    int s = 0;
    #pragma unroll
    for (int b = 0; b < 8; b++) s += p[(size_t)b * quarter];
    dis[i] = s > 0 ? rsqrtf((float)s) : 0.f;
}

// ---------------- fused setup: fill atomic + bucket scatter + x->bf16 + Wt x3 ----------------

__global__ __launch_bounds__(256) void k_setup(const int* __restrict__ row, const int* __restrict__ col,
                                               const int* __restrict__ et, const float* __restrict__ ew,
                                               int E, int* __restrict__ fill,
                                               u64* __restrict__ ep,
                                               const float* __restrict__ x, u16* __restrict__ xb, int nx4,
                                               const float* __restrict__ W1, const float* __restrict__ W2,
                                               const float* __restrict__ W3,
                                               u16* __restrict__ Wt1, u16* __restrict__ Wt2,
                                               u16* __restrict__ Wt3, int nEb, int nXb) {
    int b = blockIdx.x, tid = threadIdx.x;
    if (b < nEb) {
        int e0 = (b * 256 + tid) * 4;
        #pragma unroll
        for (int i = 0; i < 4; i++) {
            int e = e0 + i;
            if (e < E) {
                int r = row[e], c = col[e];
                int pos = atomicAdd(&fill[r], 1);
                if (pos < SLOTS)
                    ep[(size_t)r * SLOTS + pos] =
                        ((u64)__builtin_bit_cast(u32, ew[e]) << 32) | (u32)((c << 8) | et[e]);
            }
        }
    } else if (b < nEb + nXb) {
        int i = (b - nEb) * 256 + tid;
        if (i < nx4) {
            float4 v = ((const float4*)x)[i];
            ushort4 o;
            o.x = f2bf(v.x); o.y = f2bf(v.y); o.z = f2bf(v.z); o.w = f2bf(v.w);
            ((ushort4*)xb)[i] = o;
        }
    } else {
        int b2 = b - nEb - nXb;                    // 0..767
        const float* W = b2 < 256 ? W1 : (b2 < 512 ? W2 : W3);
        u16* Wt = b2 < 256 ? Wt1 : (b2 < 512 ? Wt2 : Wt3);
        int o = (b2 & 255) * 256 + tid;            // 0..65535
        int chunk = o >> 10;
        int c = (o >> 3) & 127;
        int k = chunk * 8 + (o & 7);
        Wt[o] = f2bf(W[(k >> 7) * 16384 + (k & 127) * 128 + c]);
    }
}

// ---------------- k_norm: fold norm into weights + zero-pad to x8 ----------------

__global__ __launch_bounds__(256) void k_norm(const int* __restrict__ fill,
                                              const float* __restrict__ dis,
                                              u64* __restrict__ ep, int N) {
    int wid = threadIdx.x >> 6, lane = threadIdx.x & 63;
    int n = blockIdx.x * 4 + wid;
    if (n >= N) return;
    int cnt = fill[n]; if (cnt > SLOTS) cnt = SLOTS;
    int padded = (cnt + 7) & ~7;
    float dn = dis[n];
    u64* eb = ep + (size_t)n * SLOTS;
    if (lane < cnt) {
        u64 q = eb[lane];
        u32 lo = (u32)q;
        float wgt = __builtin_bit_cast(float, (u32)(q >> 32)) * dn * dis[lo >> 8];
        eb[lane] = ((u64)__builtin_bit_cast(u32, wgt) << 32) | lo;
    } else if (lane < padded) {
        eb[lane] = 0;
    }
}

// ---------------- degree binning: group nodes by rounds so layer blocks are homogeneous ----------------
// k_bin: 64 blocks, contiguous node chunks, LDS-private 9-bin histogram
__global__ __launch_bounds__(256) void k_bin(const int* __restrict__ fill, int* __restrict__ nodeTmp,
                                             int* __restrict__ partials, int N, int chunk) {
    __shared__ int bins[9];
    if (threadIdx.x < 9) bins[threadIdx.x] = 0;
    __syncthreads();
    int s = blockIdx.x * chunk;
    int e = s + chunk; if (e > N) e = N;
    for (int n = s + threadIdx.x; n < e; n += 256) {
        int cnt = fill[n]; if (cnt > SLOTS) cnt = SLOTS;
        int r = (cnt + 7) >> 3;                     // 0..8 rounds
        int lpos = atomicAdd(&bins[r], 1);          // LDS atomic
        nodeTmp[n] = (r << 12) | lpos;              // lpos < chunk <= 782 < 4096
    }
    __syncthreads();
    if (threadIdx.x < 9) partials[blockIdx.x * 9 + threadIdx.x] = bins[threadIdx.x];
}

// k_scan9: 1 block, 9 waves; wave = bin, lane = block. base[b][r] = start[r] + prefix_b
__global__ __launch_bounds__(576) void k_scan9(const int* __restrict__ partials,
                                               int* __restrict__ base) {
    __shared__ int tot[9], start[9];
    int wid = threadIdx.x >> 6;    // bin 0..8
    int lane = threadIdx.x & 63;   // block 0..63
    int v = partials[lane * 9 + wid];
    int incl = v;
    for (int off = 1; off < 64; off <<= 1) {
        int u = __shfl_up(incl, off);
        if (lane >= off) incl += u;
    }
    if (lane == 63) tot[wid] = incl;
    __syncthreads();
    if (threadIdx.x == 0) { int s = 0; for (int r = 0; r < 9; r++) { start[r] = s; s += tot[r]; } }
    __syncthreads();
    base[lane * 9 + wid] = start[wid] + incl - v;
}

__global__ void k_place(const int* __restrict__ nodeTmp, const int* __restrict__ base,
                        int* __restrict__ order, int N, int chunk) {
    int n = blockIdx.x * 256 + threadIdx.x;
    if (n < N) {
        int v = nodeTmp[n];
        int b = n / chunk;
        int r = v >> 12, lpos = v & 4095;
        order[base[b * 9 + r] + lpos] = (r << 20) | n;   // n < 2^20
    }
}

// ---------------- fused layer: degree-ordered nodes, register bucket, uniform-base gathers ----------------

template <int MODE>
__global__ __launch_bounds__(1024, 2) void k_layer(const u16* __restrict__ src,
                                                   const int* __restrict__ order,
                                                   const u64* __restrict__ ep,
                                                   const u16* __restrict__ Wt,
                                                   const float* __restrict__ bias,
                                                   const float* __restrict__ x0,
                                                   const u16* __restrict__ z1b,
                                                   const u16* __restrict__ z2b,
                                                   float* __restrict__ outf,
                                                   u16* __restrict__ outb, int N) {
    __shared__ u16 sA[16 * 512];   // 16 KB
    __shared__ int sOrd[16];
    int tid = threadIdx.x, wid = tid >> 6, lane = tid & 63;
    int n0 = blockIdx.x * 16;

    if (wid == 0 && lane < 16) {
        int gi = n0 + lane;
        sOrd[lane] = gi < N ? (order[gi] & 0xFFFFF) : -1;
    }

    int gidx = n0 + wid;
    int ov = gidx < N ? order[gidx] : 0;
    int n = ov & 0xFFFFF;
    int padded = gidx < N ? ((ov >> 20) << 3) : 0;

    f32x2 a0 = {0.f, 0.f}, a1 = {0.f, 0.f}, a2 = {0.f, 0.f}, a3 = {0.f, 0.f};
    u64 myq = 0;
    if (lane < padded) myq = ep[(size_t)n * SLOTS + lane];
    u32 mylo = (u32)myq;
    u32 mywu = (u32)(myq >> 32);
    const char* srcc = (const char*)src;

#define RL(x, i_) ((u32)__builtin_amdgcn_readlane((int)(x), (i_)))

#define EDGE(lo_, wu_, v_) { \
        float w_  = __builtin_bit_cast(float, (u32)(wu_)); \
        f32x2 vv_; \
        vv_[0] = __builtin_bit_cast(float, (v_) << 16); \
        vv_[1] = __builtin_bit_cast(float, (v_) & 0xFFFF0000u); \
        u32 t_ = (u32)(lo_) & 3u; \
        float w0_ = t_ == 0u ? w_ : 0.f; \
        float w1_ = t_ == 1u ? w_ : 0.f; \
        float w2_ = t_ == 2u ? w_ : 0.f; \
        float w3_ = t_ == 3u ? w_ : 0.f; \
        a0 = __builtin_elementwise_fma(vv_, (f32x2){w0_, w0_}, a0); \
        a1 = __builtin_elementwise_fma(vv_, (f32x2){w1_, w1_}, a1); \
        a2 = __builtin_elementwise_fma(vv_, (f32x2){w2_, w2_}, a2); \
        a3 = __builtin_elementwise_fma(vv_, (f32x2){w3_, w3_}, a3); }

    for (int j = 0; j < padded; j += 8) {
        u32 lo[8], wu[8], v[8];
        #pragma unroll
        for (int i = 0; i < 8; i++) {
            lo[i] = RL(mylo, j + i);
            wu[i] = RL(mywu, j + i);
        }
        #pragma unroll
        for (int i = 0; i < 8; i++) {
            const u32* rowp = (const u32*)(srcc + (lo[i] & 0xFFFFFF00u));  // SALU add
            v[i] = rowp[lane];
        }
        #pragma unroll
        for (int i = 0; i < 8; i++)
            EDGE(lo[i], wu[i], v[i]);
    }
#undef EDGE
#undef RL

    // LDS store: row = wid (block-local), swizzle byte ^= (row&7)<<4
    {
        u32 X = (u32)((wid & 7) << 4);
        char* base = (char*)sA + wid * 1024;
        *(u32*)(base + ((lane * 4 + 0  ) ^ X)) = pack2bf(a0[0], a0[1]);
        *(u32*)(base + ((lane * 4 + 256) ^ X)) = pack2bf(a1[0], a1[1]);
        *(u32*)(base + ((lane * 4 + 512) ^ X)) = pack2bf(a2[0], a2[1]);
        *(u32*)(base + ((lane * 4 + 768) ^ X)) = pack2bf(a3[0], a3[1]);
    }
    __syncthreads();

    // MFMA: [16,512] @ [512,128]; waves 0..7 -> col tile wid*16
    if (wid < 8) {
        int lr = lane & 15, lk = lane >> 4;
        u32 X = (u32)((lr & 7) << 4);
        const char* ab = (const char*)sA + lr * 1024;
        const u16* bb = Wt + lk * 1024 + (wid * 16 + lr) * 8;
        f32x4 acc = {};
        #pragma unroll
        for (int ks = 0; ks < 16; ks++) {
            bf16x8 af = *(const bf16x8*)(ab + ((ks * 64 + lk * 16) ^ X));
            bf16x8 bfv = *(const bf16x8*)(bb + ks * 4096);
            acc = __builtin_amdgcn_mfma_f32_16x16x32_bf16(af, bfv, acc, 0, 0, 0);
        }

        int colg = wid * 16 + lr;
        float bv = bias[colg];
        #pragma unroll
        for (int q = 0; q < 4; q++) {
            int nn = sOrd[lk * 4 + q];
            if (nn >= 0) {
                size_t idx = (size_t)nn * DIM + colg;
                float v = acc[q] + bv;
                v = v > 0.f ? v : 0.01f * v;
                if (MODE == 1)
                    outf[idx] = 0.25f * (x0[idx] + bf2f(z1b[idx]) + bf2f(z2b[idx]) + v);
                else
                    outb[idx] = f2bf(v);
            }
        }
    }
}

// ---------------- launch ----------------

extern "C" void kernel_launch(void* const* d_in, const int* in_sizes, int n_in,
                              void* d_out, int out_size, void* d_ws, size_t ws_size,
                              hipStream_t stream) {
    const float* x     = (const float*)d_in[0];
    const int*   eidx  = (const int*)d_in[1];
    const int*   etype = (const int*)d_in[2];
    const float* eattr = (const float*)d_in[3];
    const float* W1 = (const float*)d_in[4];
    const float* b1 = (const float*)d_in[5];
    const float* W2 = (const float*)d_in[6];
    const float* b2 = (const float*)d_in[7];
    const float* W3 = (const float*)d_in[8];
    const float* b3 = (const float*)d_in[9];

    const int E = in_sizes[2];
    const int N = in_sizes[0] / DIM;
    const int* row = eidx;
    const int* col = eidx + E;

    char* w = (char*)d_ws;
    size_t off = 0;
    auto alloc = [&](size_t bytes) { size_t o = off; off = (off + bytes + 255) & ~255ULL; return o; };
    int*   fill    = (int*)(w + alloc((size_t)N * 4));
    float* dis     = (float*)(w + alloc((size_t)N * 4));
    int    quarter = (N + 3) >> 2;
    int*   part    = (int*)(w + alloc((size_t)32 * quarter * 4));
    int*   nodeTmp = (int*)(w + alloc((size_t)N * 4));
    int*   partials= (int*)(w + alloc(64 * 9 * 4));
    int*   basev   = (int*)(w + alloc(64 * 9 * 4));
    int*   order   = (int*)(w + alloc((size_t)N * 4));
    u64*   ep      = (u64*)(w + alloc((size_t)N * SLOTS * 8));
    u16*   xb      = (u16*)(w + alloc((size_t)N * DIM * 2));
    u16*   z1b     = (u16*)(w + alloc((size_t)N * DIM * 2));
    u16*   z2b     = (u16*)(w + alloc((size_t)N * DIM * 2));
    u16*   Wt1     = (u16*)(w + alloc(65536 * 2));
    u16*   Wt2     = (u16*)(w + alloc(65536 * 2));
    u16*   Wt3     = (u16*)(w + alloc(65536 * 2));

    hipMemsetAsync(fill, 0, (size_t)N * 4, stream);

    int nx4 = N * DIM / 4;
    int nEb = (E + 1023) / 1024;
    int nXb = (nx4 + 255) / 256;
    int chunk = (N + 63) / 64;

    k_hist<<<32, 1024, 0, stream>>>(col, E, part, N);
    k_dis2<<<(N + 255) / 256, 256, 0, stream>>>(part, dis, N);
    k_setup<<<nEb + nXb + 768, 256, 0, stream>>>(row, col, etype, eattr, E, fill, ep,
                                                 x, xb, nx4, W1, W2, W3, Wt1, Wt2, Wt3, nEb, nXb);
    k_norm<<<(N + 3) / 4, 256, 0, stream>>>(fill, dis, ep, N);
    k_bin<<<64, 256, 0, stream>>>(fill, nodeTmp, partials, N, chunk);
    k_scan9<<<1, 576, 0, stream>>>(partials, basev);
    k_place<<<(N + 255) / 256, 256, 0, stream>>>(nodeTmp, basev, order, N, chunk);

    int grid = (N + 15) / 16;
    k_layer<0><<<grid, 1024, 0, stream>>>(xb,  order, ep, Wt1, b1, nullptr, nullptr, nullptr, nullptr, z1b, N);
    k_layer<0><<<grid, 1024, 0, stream>>>(z1b, order, ep, Wt2, b2, nullptr, nullptr, nullptr, nullptr, z2b, N);
    k_layer<1><<<grid, 1024, 0, stream>>>(z2b, order, ep, Wt3, b3, x, z1b, z2b, (float*)d_out, nullptr, N);
}

// Round 19
// 227.936 us; speedup vs baseline: 1.0404x; 1.0404x over previous
//
#include <hip/hip_runtime.h>

#define DIM 128
#define SLOTS 64

typedef __attribute__((ext_vector_type(8))) short bf16x8;
typedef __attribute__((ext_vector_type(4))) float f32x4;
typedef __attribute__((ext_vector_type(2))) float f32x2;
typedef unsigned short u16;
typedef unsigned int u32;
typedef unsigned long long u64;

__device__ __forceinline__ float bf2f(u32 u) {
    return __builtin_bit_cast(float, u << 16);
}
__device__ __forceinline__ u16 f2bf(float f) {
    u32 u = __builtin_bit_cast(u32, f);
    u = (u + 0x7FFFu + ((u >> 16) & 1u)) >> 16;   // RNE
    return (u16)u;
}
__device__ __forceinline__ u32 pack2bf(float a, float b) {
    return (u32)f2bf(a) | ((u32)f2bf(b) << 16);
}

// ---------------- k_hist: atomic-free in-degree via LDS-privatized histograms ----------------

__global__ __launch_bounds__(1024) void k_hist(const int* __restrict__ col, int E,
                                               int* __restrict__ part, int N) {
    __shared__ int hist[12544];
    int b = blockIdx.x;            // 0..31
    int range = b >> 3;            // 0..3
    int chunk = b & 7;             // 0..7
    int quarter = (N + 3) >> 2;
    int base = range * quarter;
    int hn = N - base; if (hn > quarter) hn = quarter;
    for (int i = threadIdx.x; i < hn; i += 1024) hist[i] = 0;
    __syncthreads();
    int e0 = (int)((long long)chunk * E / 8);
    int e1 = (int)((long long)(chunk + 1) * E / 8);
    for (int e = e0 + threadIdx.x; e < e1; e += 1024) {
        int c = col[e] - base;
        if ((u32)c < (u32)hn) atomicAdd(&hist[c], 1);   // LDS atomic
    }
    __syncthreads();
    int* dst = part + (size_t)b * quarter;
    for (int i = threadIdx.x; i < hn; i += 1024) dst[i] = hist[i];
}

__global__ void k_dis2(const int* __restrict__ part, float* __restrict__ dis, int N) {
    int i = blockIdx.x * 256 + threadIdx.x;
    if (i >= N) return;
    int quarter = (N + 3) >> 2;
    int range = i / quarter;
    int il = i - range * quarter;
    const int* p = part + ((size_t)range * 8) * quarter + il;
    int s = 0;
    #pragma unroll
    for (int b = 0; b < 8; b++) s += p[(size_t)b * quarter];
    dis[i] = s > 0 ? rsqrtf((float)s) : 0.f;
}

// ---------------- fused setup: scatter with FINAL norm weight + x->bf16 + Wt x3 ----------------
// bucket lo32 = (c << 8) | et; weight = ew * dis[r] * dis[c] folded at scatter time.

__global__ __launch_bounds__(256) void k_setup(const int* __restrict__ row, const int* __restrict__ col,
                                               const int* __restrict__ et, const float* __restrict__ ew,
                                               int E, int* __restrict__ fill,
                                               const float* __restrict__ dis,
                                               u64* __restrict__ ep,
                                               const float* __restrict__ x, u16* __restrict__ xb, int nx4,
                                               const float* __restrict__ W1, const float* __restrict__ W2,
                                               const float* __restrict__ W3,
                                               u16* __restrict__ Wt1, u16* __restrict__ Wt2,
                                               u16* __restrict__ Wt3, int nEb, int nXb) {
    int b = blockIdx.x, tid = threadIdx.x;
    if (b < nEb) {
        int e0 = (b * 256 + tid) * 4;
        #pragma unroll
        for (int i = 0; i < 4; i++) {
            int e = e0 + i;
            if (e < E) {
                int r = row[e], c = col[e];
                float wgt = ew[e] * dis[r] * dis[c];
                int pos = atomicAdd(&fill[r], 1);
                if (pos < SLOTS)
                    ep[(size_t)r * SLOTS + pos] =
                        ((u64)__builtin_bit_cast(u32, wgt) << 32) | (u32)((c << 8) | et[e]);
            }
        }
    } else if (b < nEb + nXb) {
        int i = (b - nEb) * 256 + tid;
        if (i < nx4) {
            float4 v = ((const float4*)x)[i];
            ushort4 o;
            o.x = f2bf(v.x); o.y = f2bf(v.y); o.z = f2bf(v.z); o.w = f2bf(v.w);
            ((ushort4*)xb)[i] = o;
        }
    } else {
        int b2 = b - nEb - nXb;                    // 0..767
        const float* W = b2 < 256 ? W1 : (b2 < 512 ? W2 : W3);
        u16* Wt = b2 < 256 ? Wt1 : (b2 < 512 ? Wt2 : Wt3);
        int o = (b2 & 255) * 256 + tid;            // 0..65535
        int chunk = o >> 10;
        int c = (o >> 3) & 127;
        int k = chunk * 8 + (o & 7);
        Wt[o] = f2bf(W[(k >> 7) * 16384 + (k & 127) * 128 + c]);
    }
}

// ---------------- k_pad: zero-fill bucket slots [cnt, padded) ----------------

__global__ __launch_bounds__(256) void k_pad(const int* __restrict__ fill,
                                             u64* __restrict__ ep, int N) {
    int wid = threadIdx.x >> 6, lane = threadIdx.x & 63;
    int n = blockIdx.x * 4 + wid;
    if (n >= N) return;
    int cnt = fill[n]; if (cnt > SLOTS) cnt = SLOTS;
    int padded = (cnt + 7) & ~7;
    if (lane >= cnt && lane < padded)
        ep[(size_t)n * SLOTS + lane] = 0;   // zero weight, col 0, type 0
}

// ---------------- fused layer: register-resident bucket + uniform-base gathers -> LDS -> MFMA ----------------
// block = 1024 thr / 16 waves = 16 nodes, one node per wave.

template <int MODE>
__global__ __launch_bounds__(1024, 2) void k_layer(const u16* __restrict__ src,
                                                   const int* __restrict__ fill,
                                                   const u64* __restrict__ ep,
                                                   const u16* __restrict__ Wt,
                                                   const float* __restrict__ bias,
                                                   const float* __restrict__ x0,
                                                   const u16* __restrict__ z1b,
                                                   const u16* __restrict__ z2b,
                                                   float* __restrict__ outf,
                                                   u16* __restrict__ outb, int N) {
    __shared__ u16 sA[16 * 512];   // 16 KB
    int tid = threadIdx.x, wid = tid >> 6, lane = tid & 63;
    int n0 = blockIdx.x * 16;
    int n = n0 + wid;

    f32x2 a0 = {0.f, 0.f}, a1 = {0.f, 0.f}, a2 = {0.f, 0.f}, a3 = {0.f, 0.f};
    int cnt = 0;
    if (n < N) {
        cnt = fill[n];
        if (cnt > SLOTS) cnt = SLOTS;
    }
    int padded = (cnt + 7) & ~7;
    // whole bucket in registers: lane l holds slot l (masked: only live slots read)
    u64 myq = 0;
    if (lane < padded) myq = ep[(size_t)n * SLOTS + lane];
    u32 mylo = (u32)myq;
    u32 mywu = (u32)(myq >> 32);
    const char* srcc = (const char*)src;   // uniform base

#define RL(x, i_) ((u32)__builtin_amdgcn_readlane((int)(x), (i_)))

#define EDGE(lo_, wu_, v_) { \
        float w_  = __builtin_bit_cast(float, (u32)(wu_)); \
        f32x2 vv_; \
        vv_[0] = __builtin_bit_cast(float, (v_) << 16); \
        vv_[1] = __builtin_bit_cast(float, (v_) & 0xFFFF0000u); \
        u32 t_ = (u32)(lo_) & 3u; \
        float w0_ = t_ == 0u ? w_ : 0.f; \
        float w1_ = t_ == 1u ? w_ : 0.f; \
        float w2_ = t_ == 2u ? w_ : 0.f; \
        float w3_ = t_ == 3u ? w_ : 0.f; \
        a0 = __builtin_elementwise_fma(vv_, (f32x2){w0_, w0_}, a0); \
        a1 = __builtin_elementwise_fma(vv_, (f32x2){w1_, w1_}, a1); \
        a2 = __builtin_elementwise_fma(vv_, (f32x2){w2_, w2_}, a2); \
        a3 = __builtin_elementwise_fma(vv_, (f32x2){w3_, w3_}, a3); }

    for (int j = 0; j < padded; j += 8) {
        u32 lo[8], wu[8], v[8];
        #pragma unroll
        for (int i = 0; i < 8; i++) {
            lo[i] = RL(mylo, j + i);
            wu[i] = RL(mywu, j + i);
        }
        #pragma unroll
        for (int i = 0; i < 8; i++) {
            const u32* rowp = (const u32*)(srcc + (lo[i] & 0xFFFFFF00u));  // SALU add
            v[i] = rowp[lane];                                             // saddr + lane load
        }
        #pragma unroll
        for (int i = 0; i < 8; i++)
            EDGE(lo[i], wu[i], v[i]);
    }
#undef EDGE
#undef RL

    // LDS store: row = wid (node), k = t*128 + 2*lane; swizzle byte ^= (row&7)<<4
    {
        u32 X = (u32)((wid & 7) << 4);
        char* base = (char*)sA + wid * 1024;
        *(u32*)(base + ((lane * 4 + 0  ) ^ X)) = pack2bf(a0[0], a0[1]);
        *(u32*)(base + ((lane * 4 + 256) ^ X)) = pack2bf(a1[0], a1[1]);
        *(u32*)(base + ((lane * 4 + 512) ^ X)) = pack2bf(a2[0], a2[1]);
        *(u32*)(base + ((lane * 4 + 768) ^ X)) = pack2bf(a3[0], a3[1]);
    }
    __syncthreads();

    // MFMA: [16,512] @ [512,128]; waves 0..7 -> col tile wid*16
    if (wid < 8) {
        int lr = lane & 15, lk = lane >> 4;
        u32 X = (u32)((lr & 7) << 4);
        const char* ab = (const char*)sA + lr * 1024;
        const u16* bb = Wt + lk * 1024 + (wid * 16 + lr) * 8;
        f32x4 acc = {};
        #pragma unroll
        for (int ks = 0; ks < 16; ks++) {
            bf16x8 af = *(const bf16x8*)(ab + ((ks * 64 + lk * 16) ^ X));
            bf16x8 bfv = *(const bf16x8*)(bb + ks * 4096);
            acc = __builtin_amdgcn_mfma_f32_16x16x32_bf16(af, bfv, acc, 0, 0, 0);
        }

        // epilogue: col = lane&15 (+tile), row = (lane>>4)*4 + r
        int colg = wid * 16 + lr;
        float bv = bias[colg];
        #pragma unroll
        for (int r = 0; r < 4; r++) {
            int nn = n0 + lk * 4 + r;
            if (nn < N) {
                size_t idx = (size_t)nn * DIM + colg;
                float v = acc[r] + bv;
                v = v > 0.f ? v : 0.01f * v;
                if (MODE == 1)
                    outf[idx] = 0.25f * (x0[idx] + bf2f(z1b[idx]) + bf2f(z2b[idx]) + v);
                else
                    outb[idx] = f2bf(v);
            }
        }
    }
}

// ---------------- launch ----------------

extern "C" void kernel_launch(void* const* d_in, const int* in_sizes, int n_in,
                              void* d_out, int out_size, void* d_ws, size_t ws_size,
                              hipStream_t stream) {
    const float* x     = (const float*)d_in[0];
    const int*   eidx  = (const int*)d_in[1];
    const int*   etype = (const int*)d_in[2];
    const float* eattr = (const float*)d_in[3];
    const float* W1 = (const float*)d_in[4];
    const float* b1 = (const float*)d_in[5];
    const float* W2 = (const float*)d_in[6];
    const float* b2 = (const float*)d_in[7];
    const float* W3 = (const float*)d_in[8];
    const float* b3 = (const float*)d_in[9];

    const int E = in_sizes[2];
    const int N = in_sizes[0] / DIM;
    const int* row = eidx;
    const int* col = eidx + E;

    char* w = (char*)d_ws;
    size_t off = 0;
    auto alloc = [&](size_t bytes) { size_t o = off; off = (off + bytes + 255) & ~255ULL; return o; };
    int*   fill    = (int*)(w + alloc((size_t)N * 4));
    float* dis     = (float*)(w + alloc((size_t)N * 4));
    int    quarter = (N + 3) >> 2;
    int*   part    = (int*)(w + alloc((size_t)32 * quarter * 4));
    u64*   ep      = (u64*)(w + alloc((size_t)N * SLOTS * 8));
    u16*   xb      = (u16*)(w + alloc((size_t)N * DIM * 2));
    u16*   z1b     = (u16*)(w + alloc((size_t)N * DIM * 2));
    u16*   z2b     = (u16*)(w + alloc((size_t)N * DIM * 2));
    u16*   Wt1     = (u16*)(w + alloc(65536 * 2));
    u16*   Wt2     = (u16*)(w + alloc(65536 * 2));
    u16*   Wt3     = (u16*)(w + alloc(65536 * 2));

    hipMemsetAsync(fill, 0, (size_t)N * 4, stream);

    int nx4 = N * DIM / 4;
    int nEb = (E + 1023) / 1024;
    int nXb = (nx4 + 255) / 256;

    k_hist<<<32, 1024, 0, stream>>>(col, E, part, N);
    k_dis2<<<(N + 255) / 256, 256, 0, stream>>>(part, dis, N);
    k_setup<<<nEb + nXb + 768, 256, 0, stream>>>(row, col, etype, eattr, E, fill, dis, ep,
                                                 x, xb, nx4, W1, W2, W3, Wt1, Wt2, Wt3, nEb, nXb);
    k_pad<<<(N + 3) / 4, 256, 0, stream>>>(fill, ep, N);

    int grid = (N + 15) / 16;
    k_layer<0><<<grid, 1024, 0, stream>>>(xb,  fill, ep, Wt1, b1, nullptr, nullptr, nullptr, nullptr, z1b, N);
    k_layer<0><<<grid, 1024, 0, stream>>>(z1b, fill, ep, Wt2, b2, nullptr, nullptr, nullptr, nullptr, z2b, N);
    k_layer<1><<<grid, 1024, 0, stream>>>(z2b, fill, ep, Wt3, b3, x, z1b, z2b, (float*)d_out, nullptr, N);
}